// Round 5
// baseline (179.457 us; speedup 1.0000x reference)
//
#include <hip/hip_runtime.h>
#include <stdint.h>

typedef int   i32x4 __attribute__((ext_vector_type(4)));
typedef float f32x4 __attribute__((ext_vector_type(4)));

// ---------------- workspace layout (bytes) ----------------
#define WS_PART    0                         // 1536 floats: per-block absmax partials
#define WS_XQ      32768                     // 4 MB  int8 swizzled [32][16][4][128][16]
#define WS_W1QT    (WS_XQ   + 4096*1024)     // 4 MB  w1^T swizzled [32][16][4][128][16]
#define WS_W2QT    (WS_W1QT + 4096*1024)     // 4 MB  w2^T swizzled [8][64][4][128][16]
#define WS_PS      (WS_W2QT + 4096*1024)     // 16 MB plane_s swizzled [32][64][4][128][16]
#define WS_PH      (WS_PS   + 4096*4096)     // 16 MB plane_h

__device__ __forceinline__ void async16(const void* g, void* l) {
  __builtin_amdgcn_global_load_lds(
      (const __attribute__((address_space(1))) unsigned*)g,
      (__attribute__((address_space(3))) unsigned*)l, 16, 0, 0);
}

// block-wide absmax over p0[0..n0) and optional p1[0..n1); bit-exact in any order
__device__ __forceinline__ float block_absmax(const float* __restrict__ p0, int n0,
                                              const float* __restrict__ p1, int n1,
                                              float* red, float* slot) {
  int tid = threadIdx.x, nt = blockDim.x;
  float m = 0.f;
  for (int i = tid; i < n0; i += nt) m = fmaxf(m, fabsf(p0[i]));
  if (p1) for (int i = tid; i < n1; i += nt) m = fmaxf(m, fabsf(p1[i]));
  for (int off = 32; off; off >>= 1) m = fmaxf(m, __shfl_down(m, off));
  if ((tid & 63) == 0) red[tid >> 6] = m;
  __syncthreads();
  if (tid == 0) {
    int nw = nt >> 6;
    float M = red[0];
    for (int w = 1; w < nw; w++) M = fmaxf(M, red[w]);
    *slot = M;
  }
  __syncthreads();
  return *slot;
}

// ---------------- abs-max partials over x, w1f, w2f ----------------
__global__ void k_absmax3(const float* __restrict__ x, const float* __restrict__ w1,
                          const float* __restrict__ w2, float* __restrict__ part) {
  int seg = blockIdx.x >> 9;              // 0,1,2
  int b = blockIdx.x & 511;
  const float* p = (seg == 0) ? x : (seg == 1) ? w1 : w2;
  int i = b * 256 + threadIdx.x;
  float m = 0.f;
  #pragma unroll
  for (int it = 0; it < 8; it++) {
    f32x4 v = ((const f32x4*)p)[i + it * 131072];
    m = fmaxf(m, fmaxf(fmaxf(fabsf(v.x), fabsf(v.y)), fmaxf(fabsf(v.z), fabsf(v.w))));
  }
  for (int off = 32; off; off >>= 1) m = fmaxf(m, __shfl_down(m, off));
  __shared__ float red[4];
  if ((threadIdx.x & 63) == 0) red[threadIdx.x >> 6] = m;
  __syncthreads();
  if (threadIdx.x == 0)
    part[blockIdx.x] = fmaxf(fmaxf(red[0], red[1]), fmaxf(red[2], red[3]));
}

// ---------------- quantize + transpose a weight matrix (inline body) ----------------
__device__ __forceinline__ void quantT_body(const float* __restrict__ w, float s,
                                            i32x4* __restrict__ out, int C, int tkbits,
                                            int b) {
  int L = b * 256 + threadIdx.x;
  int h_in = L & 127;
  int kb = (L >> 7) & 3;
  int tk = (L >> 9) & ((1 << tkbits) - 1);
  int hblk = L >> (9 + tkbits);
  int h = hblk * 128 + h_in;
  int k0 = (tk * 4 + kb) * 16;
  int wd[4];
  #pragma unroll
  for (int d = 0; d < 4; d++) {
    unsigned acc = 0;
    #pragma unroll
    for (int j = 0; j < 4; j++) {
      float v = w[(size_t)(k0 + d * 4 + j) * C + h];
      int q = (int)rintf(v / s) & 255;
      acc |= (unsigned)q << (8 * j);
    }
    wd[d] = (int)acc;
  }
  i32x4 o; o.x = wd[0]; o.y = wd[1]; o.z = wd[2]; o.w = wd[3];
  out[L] = o;
}

// ---------------- fused prep: quant_x + quantT(w1) + quantT(w2) ----------------
__global__ void k_prep(const float* __restrict__ x, const float* __restrict__ w1f,
                       const float* __restrict__ w2f, const float* __restrict__ b1f,
                       const float* __restrict__ b2f, const float* __restrict__ part,
                       i32x4* __restrict__ xq, i32x4* __restrict__ w1qt,
                       i32x4* __restrict__ w2qt) {
  __shared__ float red[4];
  __shared__ float slot;
  int seg = blockIdx.x >> 10;             // block-uniform
  int b = blockIdx.x & 1023;
  if (seg == 0) {
    float s = block_absmax(part, 512, nullptr, 0, red, &slot) / 127.0f;
    int L = b * 256 + threadIdx.x;
    int m_in = L & 127, kb = (L >> 7) & 3, tk = (L >> 9) & 15, mblk = L >> 13;
    int m = mblk * 128 + m_in;
    int k0 = (tk * 4 + kb) * 16;
    const f32x4* px = (const f32x4*)(x + m * 1024 + k0);
    int wd[4];
    #pragma unroll
    for (int d = 0; d < 4; d++) {
      f32x4 v = px[d];
      int b0 = (int)rintf(v.x / s) & 255;
      int b1 = (int)rintf(v.y / s) & 255;
      int b2 = (int)rintf(v.z / s) & 255;
      int b3 = (int)rintf(v.w / s) & 255;
      wd[d] = b0 | (b1 << 8) | (b2 << 16) | (b3 << 24);
    }
    i32x4 o; o.x = wd[0]; o.y = wd[1]; o.z = wd[2]; o.w = wd[3];
    xq[L] = o;
  } else if (seg == 1) {
    float s = block_absmax(part + 512, 512, b1f, 4096, red, &slot) / 127.0f;
    quantT_body(w1f, s, w1qt, 4096, 4, b);
  } else {
    float s = block_absmax(part + 1024, 512, b2f, 1024, red, &slot) / 127.0f;
    quantT_body(w2f, s, w2qt, 1024, 6, b);
  }
}

// ---------------- GEMM1: o1^T = w1q^T · x_q^T ----------------
// A (w1qt) staged via global_load_lds (LDS port); B (xq) fragments loaded
// directly global->VGPR with 1-iter register prefetch (L2/TA port).
__launch_bounds__(256, 4)
__global__ void k_gemm1(const i32x4* __restrict__ Aq, const i32x4* __restrict__ Bq,
                        const float* __restrict__ part, const float* __restrict__ b1f,
                        unsigned* __restrict__ plane_s, unsigned* __restrict__ plane_h) {
  __shared__ i32x4 As[2][512];   // 16 KB: [buf][kb4][row128]
  __shared__ float red[4];
  __shared__ float slot;
  __shared__ int b1s[128];
  int tid = threadIdx.x;
  int bb = blockIdx.x;   // batch block, 0..31
  int hb = blockIdx.y;   // H block,    0..31
  int lane = tid & 63, wid = tid >> 6;
  int wm = wid & 1, wn = wid >> 1;
  int g = lane >> 4, l15 = lane & 15;

  const i32x4* gA = Aq + (size_t)hb * 16 * 512;
  const i32x4* gB = Bq + (size_t)bb * 16 * 512;

  int abase = g * 128 + wm * 64 + l15;
  int bbase = g * 128 + wn * 64 + l15;

  // prefetch A tile 0 (LDS) + B frags tile 0 (regs); latency overlaps scale phase
  async16(gA + tid, &As[0][tid]);
  async16(gA + tid + 256, &As[0][tid + 256]);
  i32x4 bnow[4], bnext[4];
  #pragma unroll
  for (int c = 0; c < 4; c++) bnow[c] = gB[bbase + c * 16];

  // recompute scales from partials (bit-identical across kernels)
  float sx  = block_absmax(part, 512, nullptr, 0, red, &slot) / 127.0f;
  float s1v = block_absmax(part + 512, 512, b1f, 4096, red, &slot) / 127.0f;
  float mult1 = sx * s1v / s1v;   // exact f32 expr as reference
  for (int i = tid; i < 128; i += 256)
    b1s[i] = (int)rintf(b1f[hb * 128 + i] / s1v);
  // block_absmax's trailing __syncthreads guarantees As[0] staged

  i32x4 acc[4][4];
  #pragma unroll
  for (int r = 0; r < 4; r++)
    #pragma unroll
    for (int c = 0; c < 4; c++) acc[r][c] = (i32x4)(0);

  for (int t = 0; t < 16; ++t) {
    int cur = t & 1;
    if (t + 1 < 16) {
      const i32x4* ga = gA + (t + 1) * 512;
      const i32x4* gb = gB + (t + 1) * 512;
      async16(ga + tid, &As[cur ^ 1][tid]);
      async16(ga + tid + 256, &As[cur ^ 1][tid + 256]);
      #pragma unroll
      for (int c = 0; c < 4; c++) bnext[c] = gb[bbase + c * 16];
    }
    i32x4 af[4];
    #pragma unroll
    for (int r = 0; r < 4; r++) af[r] = As[cur][abase + r * 16];
    #pragma unroll
    for (int r = 0; r < 4; r++)
      #pragma unroll
      for (int c = 0; c < 4; c++)
        acc[r][c] = __builtin_amdgcn_mfma_i32_16x16x64_i8(af[r], bnow[c], acc[r][c], 0, 0, 0);
    #pragma unroll
    for (int c = 0; c < 4; c++) bnow[c] = bnext[c];
    __syncthreads();   // As[cur] reads done before t+1 overwrites it; drains t+1 stage
  }

  int t2base = hb * 2 + wm;
  #pragma unroll
  for (int r = 0; r < 4; r++) {
    int hloc = wm * 64 + r * 16 + 4 * g;
    int bq0 = b1s[hloc], bq1 = b1s[hloc + 1], bq2 = b1s[hloc + 2], bq3 = b1s[hloc + 3];
    #pragma unroll
    for (int c = 0; c < 4; c++) {
      unsigned lo = 0, hi = 0;
      #pragma unroll
      for (int q = 0; q < 4; q++) {
        int y0 = acc[r][c][q];
        int bqv = (q == 0) ? bq0 : (q == 1) ? bq1 : (q == 2) ? bq2 : bq3;
        int o = (short)((int)rintf((float)y0 * mult1) + bqv);    // int16 semantics
        int a = o > 0 ? o : 0;                                   // relu
        int s8 = (int)(signed char)(a & 0xFF);
        int h8 = (a >> 8) + (s8 < 0 ? 1 : 0);                    // a = 256*h8 + s8
        lo |= (unsigned)(s8 & 0xFF) << (8 * q);
        hi |= (unsigned)(h8 & 0xFF) << (8 * q);
      }
      int m_in = wn * 64 + c * 16 + l15;
      unsigned idx = (((unsigned)(bb * 64 + t2base) * 512u + (unsigned)(r * 128 + m_in)) << 2) + g;
      plane_s[idx] = lo;
      plane_h[idx] = hi;
    }
  }
}

// ---------------- GEMM2: 64x128 tile, split-K (512 thr), B direct-to-reg ----------------
// waves 0-3: K[0,2048); waves 4-7: K[2048,4096). Planes via LDS, w2qt via registers.
__launch_bounds__(512, 4)
__global__ void k_gemm2(const i32x4* __restrict__ Ps, const i32x4* __restrict__ Ph,
                        const i32x4* __restrict__ Bq, const float* __restrict__ part,
                        const float* __restrict__ b1f, const float* __restrict__ b2f,
                        float* __restrict__ out) {
  __shared__ i32x4 st[2048];   // 32 KB: [kh][buf][ S 0-255 | H 256-511 ]; reused as merge
  __shared__ float red[8];
  __shared__ float slot;

  int tid = threadIdx.x;
  int L = blockIdx.x;
  int mb = ((L & 7) << 3) | ((L >> 3) & 7);   // same mb -> same XCD (A-strip L2 reuse)
  int nb = L >> 6;                             // 0..7
  int mblk = mb >> 1, half = mb & 1;
  int wid = tid >> 6, lane = tid & 63;
  int kh = wid >> 2, w2 = wid & 3;
  int wm = w2 & 1, wn = w2 >> 1;
  int g = lane >> 4, l15 = lane & 15;
  int t256 = tid & 255;
  int khbase = kh * 1024;
  int a_idx = (t256 >> 6) * 128 + half * 64 + (t256 & 63);
  int abase = g * 64 + wm * 32 + l15;          // within 256-slot plane tile
  int bbase = g * 128 + wn * 64 + l15;

  const i32x4* gS = Ps + (((size_t)mblk * 64 + kh * 32) << 9);
  const i32x4* gH = Ph + (((size_t)mblk * 64 + kh * 32) << 9);
  const i32x4* gB = Bq + (((size_t)nb * 64 + kh * 32) << 9);

  // prefetch tile 0: planes -> LDS buf0, B frags -> regs
  async16(gS + a_idx, &st[khbase + t256]);
  async16(gH + a_idx, &st[khbase + 256 + t256]);
  i32x4 bnow[4], bnext[4];
  #pragma unroll
  for (int c = 0; c < 4; c++) bnow[c] = gB[bbase + c * 16];

  // scales (overlaps tile-0 latency); trailing barrier guarantees buf0 staged
  float s1v = block_absmax(part + 512, 512, b1f, 4096, red, &slot) / 127.0f;
  float s2v = block_absmax(part + 1024, 512, b2f, 1024, red, &slot) / 127.0f;
  float mult2 = s1v * s2v / s2v;   // exact f32 expr as reference
  int bq[4];
  #pragma unroll
  for (int c = 0; c < 4; c++)
    bq[c] = (int)rintf(b2f[nb * 128 + wn * 64 + c * 16 + l15] / s2v);

  i32x4 accS[2][4], accH[2][4];
  #pragma unroll
  for (int r = 0; r < 2; r++)
    #pragma unroll
    for (int c = 0; c < 4; c++) { accS[r][c] = (i32x4)(0); accH[r][c] = (i32x4)(0); }

  for (int tt = 0; tt < 32; ++tt) {
    int cur = tt & 1;
    if (tt + 1 < 32) {
      const i32x4* pS = gS + ((size_t)(tt + 1) << 9);
      const i32x4* pH = gH + ((size_t)(tt + 1) << 9);
      const i32x4* pB = gB + ((size_t)(tt + 1) << 9);
      int R1 = khbase + (cur ^ 1) * 512;
      async16(pS + a_idx, &st[R1 + t256]);
      async16(pH + a_idx, &st[R1 + 256 + t256]);
      #pragma unroll
      for (int c = 0; c < 4; c++) bnext[c] = pB[bbase + c * 16];
    }
    int R = khbase + cur * 512;
    i32x4 aS[2], aH[2];
    #pragma unroll
    for (int r = 0; r < 2; r++) {
      aS[r] = st[R + abase + r * 16];
      aH[r] = st[R + 256 + abase + r * 16];
    }
    #pragma unroll
    for (int r = 0; r < 2; r++)
      #pragma unroll
      for (int c = 0; c < 4; c++) {
        accS[r][c] = __builtin_amdgcn_mfma_i32_16x16x64_i8(aS[r], bnow[c], accS[r][c], 0, 0, 0);
        accH[r][c] = __builtin_amdgcn_mfma_i32_16x16x64_i8(aH[r], bnow[c], accH[r][c], 0, 0, 0);
      }
    #pragma unroll
    for (int c = 0; c < 4; c++) bnow[c] = bnext[c];
    __syncthreads();
  }

  // merge k-halves via LDS (staging dead after final barrier); exact mod 2^32
  int* mg = (int*)st;              // 32 KB: [idx32][t256]
  if (kh == 1) {
    #pragma unroll
    for (int r = 0; r < 2; r++)
      #pragma unroll
      for (int c = 0; c < 4; c++)
        #pragma unroll
        for (int q = 0; q < 4; q++)
          mg[((r * 4 + c) * 4 + q) * 256 + t256] = accS[r][c][q] + accH[r][c][q] * 256;
  }
  __syncthreads();
  if (kh == 0) {
    #pragma unroll
    for (int r = 0; r < 2; r++) {
      int m0 = mb * 64 + wm * 32 + r * 16 + 4 * g;
      #pragma unroll
      for (int c = 0; c < 4; c++) {
        int n = nb * 128 + wn * 64 + c * 16 + l15;
        #pragma unroll
        for (int q = 0; q < 4; q++) {
          int y0 = accS[r][c][q] + accH[r][c][q] * 256
                 + mg[((r * 4 + c) * 4 + q) * 256 + t256];
          int o = (short)((int)rintf((float)y0 * mult2) + bq[c]);   // int16 semantics
          out[(size_t)(m0 + q) * 1024 + n] = (float)o * s2v;
        }
      }
    }
  }
}

extern "C" void kernel_launch(void* const* d_in, const int* in_sizes, int n_in,
                              void* d_out, int out_size, void* d_ws, size_t ws_size,
                              hipStream_t stream) {
  const float* x   = (const float*)d_in[0];
  const float* w1f = (const float*)d_in[1];
  const float* b1f = (const float*)d_in[2];
  const float* w2f = (const float*)d_in[3];
  const float* b2f = (const float*)d_in[4];
  float* out = (float*)d_out;

  char* ws = (char*)d_ws;
  float*  part    = (float*)(ws + WS_PART);
  i32x4*  xq      = (i32x4*)(ws + WS_XQ);
  i32x4*  w1qt    = (i32x4*)(ws + WS_W1QT);
  i32x4*  w2qt    = (i32x4*)(ws + WS_W2QT);
  unsigned* ps    = (unsigned*)(ws + WS_PS);
  unsigned* ph    = (unsigned*)(ws + WS_PH);

  k_absmax3<<<1536, 256, 0, stream>>>(x, w1f, w2f, part);
  k_prep<<<3072, 256, 0, stream>>>(x, w1f, w2f, b1f, b2f, part, xq, w1qt, w2qt);
  k_gemm1<<<dim3(32, 32), 256, 0, stream>>>(w1qt, xq, part, b1f, ps, ph);
  k_gemm2<<<512, 512, 0, stream>>>((const i32x4*)ps, (const i32x4*)ph, w2qt,
                                   part, b1f, b2f, out);
}